// Round 15
// baseline (136.560 us; speedup 1.0000x reference)
//
#include <hip/hip_runtime.h>
#include <cmath>

// DoubleEKVBlock on gfx950 — v5 (INSTRUMENTED round).
// L1 runs the inner loop twice (P=2, x0.5, CSE-defeated by runtime-zero z) to push
// it above the harness fill ops' ~40us so its rocprof counters become visible in
// top-5. L2 is v4-identical as timing control. Math unchanged otherwise.

constexpr int Cc = 32, Oc = 32, Hc = 32, Wc = 32;
constexpr int OT = 4;       // output channels per block
constexpr int WTILE = 16;   // output columns per block
constexpr int TPB = 256;    // 4 waves: lane->(ol,s), wave->c-split
constexpr int THS = 578;    // per-ol theta stride in floats (288 f2 pairs + 1 pad pair)

// MODE 0: stage applies vm(sc_in,bi_in); epilogue applies vm(sc_out,bi_out) -> ws
// MODE 1: stage raw (already mapped); epilogue: relu(y + identity) -> out
// P: passes over the inner loop (P=2 doubles trans work, result averaged — diagnostic)
template <int MODE, int P>
__global__ __launch_bounds__(TPB, 8)
void ekv_pass(const float* __restrict__ vin,
              const float* __restrict__ thp,
              const float* __restrict__ thn,
              float* __restrict__ vout,
              const float* __restrict__ sc_in,
              const float* __restrict__ bi_in,
              const float* __restrict__ sc_out,
              const float* __restrict__ bi_out,
              const float* __restrict__ ident,
              float K1f, float EMS, float GAIN, float z)
{
    __shared__ float thL[OT * THS];                // {2^(74-tpK1), 2^(74-tnK1)} pairs: 9.25 KB
    __shared__ float xv[3 * Cc * (WTILE + 2) + 4]; // x*K1-74: 6.77 KB
    __shared__ float red[4][64];                   // c-split partials: 1 KB

    const int t  = threadIdx.x;
    const int bx = blockIdx.x;          // 16 = 8 ot * 2 wt
    const int ot = bx >> 1, wt = bx & 1;
    const int h  = blockIdx.y;
    const int n  = blockIdx.z;
    const int o0 = ot * OT;
    const int w0 = wt * WTILE;

    // ---- stage thetas: 4 o x 288 pairs -> T = 2^(74 - theta*K1) ----
    const float* tp_g = thp + o0 * 288;
    const float* tn_g = thn + o0 * 288;
#pragma unroll
    for (int k = 0; k < 5; ++k) {             // 1152 pairs, 5*256 with guard
        int idx = t + k * TPB;
        if (idx < OT * 288) {
            int ol = idx / 288, j = idx % 288;
            thL[ol * THS + 2 * j]     = __builtin_amdgcn_exp2f(fmaf(tp_g[idx], -K1f, 74.f));
            thL[ol * THS + 2 * j + 1] = __builtin_amdgcn_exp2f(fmaf(tn_g[idx], -K1f, 74.f));
        }
    }

    // ---- stage input tile: 3 rows x 32 ch x 18 cols -> x*K1 - 74 (zero halo) ----
#pragma unroll
    for (int k = 0; k < 7; ++k) {
        int idx = t + k * TPB;
        if (idx < 3 * Cc * (WTILE + 2)) {     // 1728
            int dh = idx / (Cc * (WTILE + 2));
            int r  = idx % (Cc * (WTILE + 2));
            int c  = r / (WTILE + 2);
            int i  = r % (WTILE + 2);
            int hh = h + dh - 1;
            int ww = w0 + i - 1;
            float v = 0.f;
            if (hh >= 0 && hh < Hc && ww >= 0 && ww < Wc) {
                v = vin[((n * Cc + c) * Hc + hh) * Wc + ww];
                if (MODE == 0) {
                    float rs = fminf(fmaxf(fabsf(sc_in[c]), 0.01f), 3.0f);
                    v = fminf(fmaxf(fmaf(v, rs, bi_in[c]), 0.f), 8.f);
                }
            }
            xv[idx] = fmaf(v, K1f, -74.f);
        }
    }
    __syncthreads();

    // ---- main: lane -> (ol, s); wave -> c-split of 8 channels ----
    const int ol = t & (OT - 1);          // 4 o's: distinct theta bank-pairs
    const int s  = (t >> 2) & 15;         // 16 cols: stride-1 xv, 4-lane broadcast
    const int cs = t >> 6;                // wave id: channels [8cs, 8cs+8)

    const float2* th2 = (const float2*)&thL[ol * THS];
    float acc1 = 0.f, acc2 = 0.f;
    for (int p = 0; p < P; ++p) {
        const float zoff = (P > 1) ? z * (float)p : 0.f;  // runtime 0: defeats CSE across passes
        for (int c = cs * 8; c < cs * 8 + 8; ++c) {
#pragma unroll
            for (int kh = 0; kh < 3; ++kh) {
                const float* xr = &xv[(kh * Cc + c) * (WTILE + 2) + s];
                const float2* tq = &th2[(c * 3 + kh) * 3];
#pragma unroll
                for (int kw = 0; kw < 3; ++kw) {
                    float  xk = (P > 1) ? (xr[kw] + zoff) : xr[kw];
                    float  E  = __builtin_amdgcn_exp2f(xk);   // 2^(xk-74), one per tuple
                    float2 th = tq[kw];                        // {Tp, Tn}, one b64
                    float ep  = E * th.x;                      // 2^(xk - tp*K1)
                    float lap = __builtin_amdgcn_logf(1.f + ep);
                    float lbp = __builtin_amdgcn_logf(fmaf(ep, EMS, 1.f));
                    acc1 = fmaf(lap, lap, acc1);
                    acc2 = fmaf(lbp, lbp, acc2);
                    float en  = E * th.y;                      // 2^(xk - tn*K1)
                    float lan = __builtin_amdgcn_logf(1.f + en);
                    float lbn = __builtin_amdgcn_logf(fmaf(en, EMS, 1.f));
                    acc2 = fmaf(lan, lan, acc2);
                    acc1 = fmaf(lbn, lbn, acc1);
                }
            }
        }
    }
    red[cs][t & 63] = (acc1 - acc2) * (P > 1 ? (1.f / (float)P) : 1.f);
    __syncthreads();

    // ---- reduce 4 partials + epilogue: threads 0..63 ----
    if (t < 64) {
        float y = (red[0][t] + red[1][t] + red[2][t] + red[3][t]) * GAIN;
        const int eol = t & (OT - 1);
        const int es  = t >> 2;
        const int w = w0 + es;
        const int o = o0 + eol;
        const int oidx = ((n * Oc + o) * Hc + h) * Wc + w;
        if (MODE == 0) {
            float rs = fminf(fmaxf(fabsf(sc_out[o]), 0.01f), 3.0f);
            vout[oidx] = fminf(fmaxf(fmaf(y, rs, bi_out[o]), 0.f), 8.f);
        } else {
            vout[oidx] = fmaxf(y + ident[oidx], 0.f);
        }
    }
}

extern "C" void kernel_launch(void* const* d_in, const int* in_sizes, int n_in,
                              void* d_out, int out_size, void* d_ws, size_t ws_size,
                              hipStream_t stream) {
    const float* x      = (const float*)d_in[0];
    const float* scale1 = (const float*)d_in[1];
    const float* bias1  = (const float*)d_in[2];
    const float* tp1    = (const float*)d_in[3];
    const float* tn1    = (const float*)d_in[4];
    const float* scale2 = (const float*)d_in[5];
    const float* bias2  = (const float*)d_in[6];
    const float* tp2    = (const float*)d_in[7];
    const float* tn2    = (const float*)d_in[8];
    float* out = (float*)d_out;
    float* v2  = (float*)d_ws;   // 512 KB intermediate (mapped layer-1 output)

    const double PHI  = 2.0 * 1.5 * 0.026;                  // 0.078
    const float  K1f  = (float)(1.4426950408889634 / PHI);  // invPHI * log2(e)
    const float  EMS  = (float)exp(-0.2 / PHI);             // e^{-VD/PHI}
    const float  GAIN = (float)(0.02 * 0.6931471805599453 * 0.6931471805599453); // ALPHA*TIA*ln2^2

    dim3 grid(16, Hc, 4), block(TPB);   // 2048 blocks x 4 waves
    // L1: P=2 diagnostic (doubled inner work, averaged — pushes dur > fill ops
    // so rocprof top-5 finally shows our counters). z=0.0f at runtime.
    ekv_pass<0, 2><<<grid, block, 0, stream>>>(x,  tp1, tn1, v2,  scale1, bias1, scale2, bias2, nullptr,
                                               K1f, EMS, GAIN, 0.0f);
    // L2: v4-identical control.
    ekv_pass<1, 1><<<grid, block, 0, stream>>>(v2, tp2, tn2, out, nullptr, nullptr, nullptr, nullptr, x,
                                               K1f, EMS, GAIN, 0.0f);
}

// Round 18
// 115.060 us; speedup vs baseline: 1.1869x; 1.1869x over previous
//
#include <hip/hip_runtime.h>
#include <cmath>

// DoubleEKVBlock on gfx950 — v6b (v6 + xv pad; v6 core-dumped, audit found all
// global accesses in-bounds — only suspect was compiler-widened LDS reads
// touching xv[3264], so the +4 pad from v4/v5 is restored).
// v5 counters: VGPR=28, VALUBusy 76%, Occ 50%, inner ~15us/pass, FIXED ~21us.
// v6 attacks fixed cost: pow2-only staging index math (no /288, /18 magic-div),
// theta staging halved (OT=2), full-width 32-col tile. Inner loop = v4/v5.

constexpr int Cc = 32, Oc = 32, Hc = 32, Wc = 32;
constexpr int OT = 2;       // output channels per block
constexpr int TPB = 256;    // 4 waves; wave = c-chunk of 8; lane = (ol, w)
constexpr int THS = 578;    // per-ol theta stride in floats (288 f2 pairs + 1 pad)
constexpr int XROW = 34;    // x row stride: 32 cols + 2 halo

// MODE 0: stage applies vm(sc_in,bi_in); epilogue applies vm(sc_out,bi_out) -> ws
// MODE 1: stage raw (already mapped); epilogue: relu(y + identity) -> out
template <int MODE>
__global__ __launch_bounds__(TPB, 8)
void ekv_pass(const float* __restrict__ vin,
              const float* __restrict__ thp,
              const float* __restrict__ thn,
              float* __restrict__ vout,
              const float* __restrict__ sc_in,
              const float* __restrict__ bi_in,
              const float* __restrict__ sc_out,
              const float* __restrict__ bi_out,
              const float* __restrict__ ident,
              float K1f, float EMS, float GAIN)
{
    __shared__ float thL[OT * THS];         // {2^(74-tpK1), 2^(74-tnK1)} pairs: 4.6 KB
    __shared__ float xv[3 * Cc * XROW + 4]; // x*K1-74, rows h-1..h+1, halo cols (+pad)
    __shared__ float red[4][64];            // c-split partials: 1 KB

    const int t  = threadIdx.x;
    const int ot = blockIdx.x;          // 16: o-pairs
    const int h  = blockIdx.y;
    const int n  = blockIdx.z;
    const int o0 = ot * OT;

    // ---- stage thetas: pow2 mapping, wave-half ol = t>>7, j = (t&127)+128k ----
    {
        const int ol = t >> 7;
        const float* tp_g = thp + (o0 + ol) * 288;
        const float* tn_g = thn + (o0 + ol) * 288;
        float* dst = &thL[ol * THS];
#pragma unroll
        for (int k = 0; k < 3; ++k) {
            int j = (t & 127) + 128 * k;
            if (j < 288) {
                dst[2 * j]     = __builtin_amdgcn_exp2f(fmaf(tp_g[j], -K1f, 74.f));
                dst[2 * j + 1] = __builtin_amdgcn_exp2f(fmaf(tn_g[j], -K1f, 74.f));
            }
        }
    }

    // ---- stage x: 12 pow2 passes (row=(t>>5)+8k, w=t&31) + no-load halo pass ----
    {
        const int w = t & 31;
#pragma unroll
        for (int k = 0; k < 12; ++k) {
            int row = (t >> 5) + 8 * k;       // row = dh*32 + c, 0..95
            int dh  = row >> 5;
            int c   = row & 31;
            int hh  = h + dh - 1;
            float v = 0.f;
            if (hh >= 0 && hh < Hc) {
                v = vin[((n * Cc + c) * Hc + hh) * Wc + w];
                if (MODE == 0) {
                    float rs = fminf(fmaxf(fabsf(sc_in[c]), 0.01f), 3.0f);
                    v = fminf(fmaxf(fmaf(v, rs, bi_in[c]), 0.f), 8.f);
                }
            }
            xv[row * XROW + 1 + w] = fmaf(v, K1f, -74.f);
        }
        if (t < 192) {                        // halo cols w=-1,32: x=0 -> xk=-74
            int row  = t >> 1;                // dh*32+c
            int side = t & 1;
            xv[row * XROW + (side ? 33 : 0)] = -74.f;
        }
    }
    __syncthreads();

    // ---- main: lane l=(ol,w); wave cs = c-chunk of 8 ----
    const int l  = t & 63;
    const int w  = l & 31;
    const int ol = l >> 5;
    const int cs = t >> 6;

    const float2* th2 = (const float2*)&thL[ol * THS];
    float acc1 = 0.f, acc2 = 0.f;
    for (int c = cs * 8; c < cs * 8 + 8; ++c) {
#pragma unroll
        for (int kh = 0; kh < 3; ++kh) {
            const float* xr = &xv[(kh * Cc + c) * XROW + w];   // xr[kw] = col w-1+kw
            const float2* tq = &th2[(c * 3 + kh) * 3];
#pragma unroll
            for (int kw = 0; kw < 3; ++kw) {
                float  E  = __builtin_amdgcn_exp2f(xr[kw]);    // 2^(xk-74), shared
                float2 th = tq[kw];                            // {Tp, Tn}, one b64
                float ep  = E * th.x;                          // 2^(xk - tp*K1)
                float lap = __builtin_amdgcn_logf(1.f + ep);
                float lbp = __builtin_amdgcn_logf(fmaf(ep, EMS, 1.f));
                acc1 = fmaf(lap, lap, acc1);
                acc2 = fmaf(lbp, lbp, acc2);
                float en  = E * th.y;                          // 2^(xk - tn*K1)
                float lan = __builtin_amdgcn_logf(1.f + en);
                float lbn = __builtin_amdgcn_logf(fmaf(en, EMS, 1.f));
                acc2 = fmaf(lan, lan, acc2);
                acc1 = fmaf(lbn, lbn, acc1);
            }
        }
    }
    red[cs][l] = acc1 - acc2;
    __syncthreads();

    // ---- reduce 4 partials + epilogue: threads 0..63 (2 o x 32 w) ----
    if (t < 64) {
        float y = (red[0][t] + red[1][t] + red[2][t] + red[3][t]) * GAIN;
        const int o  = o0 + (t >> 5);
        const int ww = t & 31;
        const int oidx = ((n * Oc + o) * Hc + h) * Wc + ww;
        if (MODE == 0) {
            float rs = fminf(fmaxf(fabsf(sc_out[o]), 0.01f), 3.0f);
            vout[oidx] = fminf(fmaxf(fmaf(y, rs, bi_out[o]), 0.f), 8.f);
        } else {
            vout[oidx] = fmaxf(y + ident[oidx], 0.f);
        }
    }
}

extern "C" void kernel_launch(void* const* d_in, const int* in_sizes, int n_in,
                              void* d_out, int out_size, void* d_ws, size_t ws_size,
                              hipStream_t stream) {
    const float* x      = (const float*)d_in[0];
    const float* scale1 = (const float*)d_in[1];
    const float* bias1  = (const float*)d_in[2];
    const float* tp1    = (const float*)d_in[3];
    const float* tn1    = (const float*)d_in[4];
    const float* scale2 = (const float*)d_in[5];
    const float* bias2  = (const float*)d_in[6];
    const float* tp2    = (const float*)d_in[7];
    const float* tn2    = (const float*)d_in[8];
    float* out = (float*)d_out;
    float* v2  = (float*)d_ws;   // 512 KB intermediate (mapped layer-1 output)

    const double PHI  = 2.0 * 1.5 * 0.026;                  // 0.078
    const float  K1f  = (float)(1.4426950408889634 / PHI);  // invPHI * log2(e)
    const float  EMS  = (float)exp(-0.2 / PHI);             // e^{-VD/PHI}
    const float  GAIN = (float)(0.02 * 0.6931471805599453 * 0.6931471805599453); // ALPHA*TIA*ln2^2

    dim3 grid(16, Hc, 4), block(TPB);   // 2048 blocks x 4 waves
    ekv_pass<0><<<grid, block, 0, stream>>>(x,  tp1, tn1, v2,  scale1, bias1, scale2, bias2, nullptr,
                                            K1f, EMS, GAIN);
    ekv_pass<1><<<grid, block, 0, stream>>>(v2, tp2, tn2, out, nullptr, nullptr, nullptr, nullptr, x,
                                            K1f, EMS, GAIN);
}